// Round 3
// baseline (652.573 us; speedup 1.0000x reference)
//
#include <hip/hip_runtime.h>
#include <hip/hip_bf16.h>

// Problem constants (B=8, S=4096, D=1024, H=16, hd=64). All I/O is FLOAT32.
#define TOKENS   32768
#define DMODEL   1024
#define THREE_D  3072

using u16 = unsigned short;
typedef __attribute__((ext_vector_type(8))) short short8;  // 8 bf16 = 4 VGPRs
typedef __attribute__((ext_vector_type(4))) float f32x4;

__device__ __forceinline__ float bf2f(u16 u) {
  union { unsigned int i; float f; } v; v.i = ((unsigned int)u) << 16; return v.f;
}
__device__ __forceinline__ u16 f2bf(float f) {
  __hip_bfloat16 h = __float2bfloat16(f);   // RNE
  return *reinterpret_cast<u16*>(&h);
}

// async global->LDS, 16B per lane; LDS dest = wave-uniform base + lane*16
__device__ __forceinline__ void gload_lds16(const u16* g, u16* l) {
  __builtin_amdgcn_global_load_lds((const __attribute__((address_space(1))) void*)g,
                                   (__attribute__((address_space(3))) void*)l,
                                   16, 0, 0);
}

// ---------------------------------------------------------------------------
// f32 -> bf16 elementwise convert (n divisible by 1024)
// ---------------------------------------------------------------------------
__global__ __launch_bounds__(256) void convert_f32_bf16(const float* __restrict__ in,
                                                        u16* __restrict__ out, long n) {
  long i = ((long)blockIdx.x * 256 + threadIdx.x) * 4;
  if (i >= n) return;
  float4 v = *reinterpret_cast<const float4*>(in + i);
  ushort4 o;
  o.x = f2bf(v.x); o.y = f2bf(v.y); o.z = f2bf(v.z); o.w = f2bf(v.w);
  *reinterpret_cast<ushort4*>(out + i) = o;
}

// ---------------------------------------------------------------------------
// f32 in (R x C) -> bf16 out (C x R) transpose+convert. R, C multiples of 32.
// ---------------------------------------------------------------------------
__global__ __launch_bounds__(256) void transpose_convert(const float* __restrict__ in,
                                                         u16* __restrict__ out,
                                                         int R, int C) {
  __shared__ u16 tile[32][33];  // +1 pad breaks bank conflicts
  const int bc = blockIdx.x * 32;
  const int br = blockIdx.y * 32;
  const int tx = threadIdx.x & 31;
  const int ty = threadIdx.x >> 5;  // 0..7
  #pragma unroll
  for (int i = 0; i < 32; i += 8)
    tile[ty + i][tx] = f2bf(in[(long)(br + ty + i) * C + bc + tx]);
  __syncthreads();
  #pragma unroll
  for (int i = 0; i < 32; i += 8)
    out[(long)(bc + ty + i) * R + br + tx] = tile[tx][ty + i];
}

// ---------------------------------------------------------------------------
// C(M,N) = A(M,K) @ BT(N,K)^T + bias(N).  A,BT bf16; bias f32; MFMA f32 acc.
// Output: f32 if OUT_F32 else bf16.  128x128 tile, 4 waves, 4x4 16x16x32 MFMA.
// A read through column remap: logical col c -> row*a_stride + (c>>6)*a_grp + (c&63).
// Identity: a_stride=K, a_grp=64.  M%128==0, N%128==0, K%32==0.
// ---------------------------------------------------------------------------
#define BM 128
#define BN 128
#define BK 32

template <bool OUT_F32>
__global__ __launch_bounds__(256) void gemm_bt_bias(
    const u16* __restrict__ A, const u16* __restrict__ BT,
    const float* __restrict__ bias, void* __restrict__ Cv,
    int M, int N, int K, long a_stride, int a_grp) {
  __shared__ alignas(16) u16 As[BM * BK];  // 8 KB
  __shared__ alignas(16) u16 Bs[BN * BK];  // 8 KB

  const int tiles_n = N / BN;
  const int bm = (blockIdx.x / tiles_n) * BM;
  const int bn = (blockIdx.x % tiles_n) * BN;
  const int tid  = threadIdx.x;
  const int wave = tid >> 6;
  const int lane = tid & 63;
  const int wm   = (wave & 1) * 64;
  const int wn   = (wave >> 1) * 64;
  const int lrow = lane & 15;
  const int kq   = (lane >> 4) * 8;

  // staging geometry: per wave, 2 chunks of 16 rows; lane L -> row L/4, kcol (L&3)*8
  const int srow = wave * 32 + (lane >> 2);
  const int scol = (lane & 3) * 8;
  u16* alds0 = As + (wave * 32) * BK;       // wave-uniform LDS bases
  u16* alds1 = As + (wave * 32 + 16) * BK;
  u16* blds0 = Bs + (wave * 32) * BK;
  u16* blds1 = Bs + (wave * 32 + 16) * BK;

  f32x4 acc[4][4];
  #pragma unroll
  for (int i = 0; i < 4; i++)
    #pragma unroll
    for (int j = 0; j < 4; j++) acc[i][j] = (f32x4){0.f, 0.f, 0.f, 0.f};

  for (int k0 = 0; k0 < K; k0 += BK) {
    const int c = k0 + scol;                       // multiple of 8; run stays in one 64-group
    const long aoff = (long)(c >> 6) * a_grp + (c & 63);
    __syncthreads();  // prior compute done before LDS overwrite
    gload_lds16(A  + (long)(bm + srow)      * a_stride + aoff, alds0);
    gload_lds16(A  + (long)(bm + srow + 16) * a_stride + aoff, alds1);
    gload_lds16(BT + (long)(bn + srow)      * K + k0 + scol, blds0);
    gload_lds16(BT + (long)(bn + srow + 16) * K + k0 + scol, blds1);
    __syncthreads();  // drains vmcnt before ds_read

    short8 a[4], b[4];
    #pragma unroll
    for (int mi = 0; mi < 4; mi++)
      a[mi] = *reinterpret_cast<const short8*>(&As[(wm + mi * 16 + lrow) * BK + kq]);
    #pragma unroll
    for (int ni = 0; ni < 4; ni++)
      b[ni] = *reinterpret_cast<const short8*>(&Bs[(wn + ni * 16 + lrow) * BK + kq]);
    #pragma unroll
    for (int mi = 0; mi < 4; mi++)
      #pragma unroll
      for (int ni = 0; ni < 4; ni++)
        acc[mi][ni] = __builtin_amdgcn_mfma_f32_16x16x32_bf16(a[mi], b[ni], acc[mi][ni], 0, 0, 0);
  }

  // epilogue: C/D layout col = lane&15, row = (lane>>4)*4 + r
  #pragma unroll
  for (int ni = 0; ni < 4; ni++) {
    const int col = bn + wn + ni * 16 + lrow;
    const float bv = bias[col];
    #pragma unroll
    for (int mi = 0; mi < 4; mi++) {
      #pragma unroll
      for (int r = 0; r < 4; r++) {
        const int row = bm + wm + mi * 16 + (lane >> 4) * 4 + r;
        const float val = acc[mi][ni][r] + bv;
        if (OUT_F32)
          ((float*)Cv)[(long)row * N + col] = val;
        else
          ((u16*)Cv)[(long)row * N + col] = f2bf(val);
      }
    }
  }
}

// ---------------------------------------------------------------------------
// Per-token attention across the 16 heads. One wave per token.
// qkv row layout: head h -> q at h*192, k at h*192+64, v at h*192+128.
// scores(16x16) via 2 MFMAs straight from global, softmax via intra-quad
// shuffles, PV via VALU with P staged in LDS.  Output written IN PLACE into
// the q-slots (q fully consumed into registers before the write; v disjoint).
// ---------------------------------------------------------------------------
__global__ __launch_bounds__(256) void attn_local(u16* __restrict__ qkv) {
  __shared__ float p_s[4][16][16];
  const int tid  = threadIdx.x;
  const int wave = tid >> 6;
  const int lane = tid & 63;
  const int t    = blockIdx.x * 4 + wave;
  u16* row = qkv + (long)t * THREE_D;
  const int lrow = lane & 15;
  const int quad = lane >> 4;
  const int kq   = quad * 8;

  // A-frag: q[m=lrow][d], B-frag: k[n=lrow][d]  (d = quad*8+j, two 32-chunks)
  short8 a0 = *reinterpret_cast<const short8*>(row + lrow * 192 + kq);
  short8 a1 = *reinterpret_cast<const short8*>(row + lrow * 192 + 32 + kq);
  short8 b0 = *reinterpret_cast<const short8*>(row + lrow * 192 + 64 + kq);
  short8 b1 = *reinterpret_cast<const short8*>(row + lrow * 192 + 96 + kq);
  f32x4 s = {0.f, 0.f, 0.f, 0.f};
  s = __builtin_amdgcn_mfma_f32_16x16x32_bf16(a0, b0, s, 0, 0, 0);
  s = __builtin_amdgcn_mfma_f32_16x16x32_bf16(a1, b1, s, 0, 0, 0);

  const float scale = 0.125f;  // 1/sqrt(64)
  float p[4];
  #pragma unroll
  for (int r = 0; r < 4; r++) {
    // score row i = quad*4+r lives in the 16 lanes of this quad (col = lane&15)
    float x = s[r] * scale;
    float m = x;
    #pragma unroll
    for (int mask = 1; mask < 16; mask <<= 1) m = fmaxf(m, __shfl_xor(m, mask));
    float e = __expf(x - m);
    float l = e;
    #pragma unroll
    for (int mask = 1; mask < 16; mask <<= 1) l += __shfl_xor(l, mask);
    p[r] = e / l;
  }
  #pragma unroll
  for (int r = 0; r < 4; r++) p_s[wave][quad * 4 + r][lrow] = p[r];
  __syncthreads();  // all 4 waves participate (grid is exact)

  // O[i][d=lane] = sum_j P[i][j] * v[j][d]
  float o[16];
  #pragma unroll
  for (int i = 0; i < 16; i++) o[i] = 0.f;
  #pragma unroll
  for (int j = 0; j < 16; j++) {
    float vj = bf2f(row[j * 192 + 128 + lane]);
    #pragma unroll
    for (int i = 0; i < 16; i++) o[i] += p_s[wave][i][j] * vj;
  }
  // in-place write into q-slots: head i, dim lane
  #pragma unroll
  for (int i = 0; i < 16; i++)
    row[i * 192 + lane] = f2bf(o[i]);
}

// ---------------------------------------------------------------------------
extern "C" void kernel_launch(void* const* d_in, const int* in_sizes, int n_in,
                              void* d_out, int out_size, void* d_ws, size_t ws_size,
                              hipStream_t stream) {
  const float* x     = (const float*)d_in[0];  // (T, 1024) f32
  const float* W_qkv = (const float*)d_in[1];  // (1024, 3072) f32
  const float* b_qkv = (const float*)d_in[2];  // (3072) f32
  const float* W_out = (const float*)d_in[3];  // (1024, 1024) f32
  const float* b_out = (const float*)d_in[4];  // (1024) f32
  float* out = (float*)d_out;                  // (T, 1024) f32

  // workspace carve-up: 264 MiB total
  char* ws = (char*)d_ws;
  u16* qkv   = (u16*)ws;  ws += (size_t)TOKENS * THREE_D * 2;   // 192 MiB
  u16* x_bf  = (u16*)ws;  ws += (size_t)TOKENS * DMODEL * 2;    //  64 MiB
  u16* wqkvT = (u16*)ws;  ws += (size_t)THREE_D * DMODEL * 2;   //   6 MiB
  u16* woutT = (u16*)ws;                                        //   2 MiB

  dim3 tb(256);
  convert_f32_bf16<<<dim3((TOKENS * DMODEL) / 1024), tb, 0, stream>>>(
      x, x_bf, (long)TOKENS * DMODEL);
  transpose_convert<<<dim3(THREE_D / 32, DMODEL / 32), tb, 0, stream>>>(W_qkv, wqkvT, DMODEL, THREE_D);
  transpose_convert<<<dim3(DMODEL / 32, DMODEL / 32), tb, 0, stream>>>(W_out, woutT, DMODEL, DMODEL);
  // GEMM1: qkv = x @ W_qkv + b_qkv   (bf16 out, identity A-map)
  gemm_bt_bias<false><<<dim3((TOKENS / BM) * (THREE_D / BN)), tb, 0, stream>>>(
      x_bf, wqkvT, b_qkv, qkv, TOKENS, THREE_D, DMODEL, (long)DMODEL, 64);
  // attention (in place: output -> q-slots of qkv)
  attn_local<<<dim3(TOKENS / 4), tb, 0, stream>>>(qkv);
  // GEMM2: out = vals @ W_out + b_out  (f32 out; A = q-slots: stride 3072, group 192)
  gemm_bt_bias<true><<<dim3((TOKENS / BM) * (DMODEL / BN)), tb, 0, stream>>>(
      qkv, woutT, b_out, out, TOKENS, DMODEL, DMODEL, (long)THREE_D, 192);
}

// Round 4
// 646.212 us; speedup vs baseline: 1.0098x; 1.0098x over previous
//
#include <hip/hip_runtime.h>
#include <hip/hip_bf16.h>

// Problem constants (B=8, S=4096, D=1024, H=16, hd=64). All I/O is FLOAT32.
#define TOKENS   32768
#define DMODEL   1024
#define THREE_D  3072

using u16 = unsigned short;
typedef __attribute__((ext_vector_type(8))) short short8;  // 8 bf16 = 4 VGPRs
typedef __attribute__((ext_vector_type(4))) float f32x4;

__device__ __forceinline__ float bf2f(u16 u) {
  union { unsigned int i; float f; } v; v.i = ((unsigned int)u) << 16; return v.f;
}
__device__ __forceinline__ u16 f2bf(float f) {
  __hip_bfloat16 h = __float2bfloat16(f);   // RNE
  return *reinterpret_cast<u16*>(&h);
}

// async global->LDS, 16B per lane; LDS dest = wave-uniform base + lane*16
__device__ __forceinline__ void gload_lds16(const u16* g, u16* l) {
  __builtin_amdgcn_global_load_lds((const __attribute__((address_space(1))) void*)g,
                                   (__attribute__((address_space(3))) void*)l,
                                   16, 0, 0);
}

// ---------------------------------------------------------------------------
// f32 -> bf16 elementwise convert (n divisible by 1024)
// ---------------------------------------------------------------------------
__global__ __launch_bounds__(256) void convert_f32_bf16(const float* __restrict__ in,
                                                        u16* __restrict__ out, long n) {
  long i = ((long)blockIdx.x * 256 + threadIdx.x) * 4;
  if (i >= n) return;
  float4 v = *reinterpret_cast<const float4*>(in + i);
  ushort4 o;
  o.x = f2bf(v.x); o.y = f2bf(v.y); o.z = f2bf(v.z); o.w = f2bf(v.w);
  *reinterpret_cast<ushort4*>(out + i) = o;
}

// ---------------------------------------------------------------------------
// f32 in (R x C) -> bf16 out (C x R) transpose+convert. R, C multiples of 32.
// ---------------------------------------------------------------------------
__global__ __launch_bounds__(256) void transpose_convert(const float* __restrict__ in,
                                                         u16* __restrict__ out,
                                                         int R, int C) {
  __shared__ u16 tile[32][33];  // +1 pad breaks bank conflicts
  const int bc = blockIdx.x * 32;
  const int br = blockIdx.y * 32;
  const int tx = threadIdx.x & 31;
  const int ty = threadIdx.x >> 5;  // 0..7
  #pragma unroll
  for (int i = 0; i < 32; i += 8)
    tile[ty + i][tx] = f2bf(in[(long)(br + ty + i) * C + bc + tx]);
  __syncthreads();
  #pragma unroll
  for (int i = 0; i < 32; i += 8)
    out[(long)(bc + ty + i) * R + br + tx] = tile[tx][ty + i];
}

// ---------------------------------------------------------------------------
// C(M,N) = A(M,K) @ BT(N,K)^T + bias(N).  A,BT bf16; bias f32; MFMA f32 acc.
// Output: f32 if OUT_F32 else bf16.  128x128 tile, 4 waves, BK=64 (32 MFMAs
// per barrier pair), XOR-swizzled LDS staging (bank-conflict-free ds_read).
// A read through column remap: logical col c -> row*a_stride + (c>>6)*a_grp + (c&63).
// Identity: a_stride=K, a_grp=64.  M%128==0, N%128==0, K%64==0.
// ---------------------------------------------------------------------------
#define BM 128
#define BN 128
#define BK 64

template <bool OUT_F32>
__global__ __launch_bounds__(256) void gemm_bt_bias(
    const u16* __restrict__ A, const u16* __restrict__ BT,
    const float* __restrict__ bias, void* __restrict__ Cv,
    int M, int N, int K, long a_stride, int a_grp) {
  __shared__ alignas(16) u16 As[BM * BK];  // 16 KB
  __shared__ alignas(16) u16 Bs[BN * BK];  // 16 KB

  const int tiles_n = N / BN;
  const int bm = (blockIdx.x / tiles_n) * BM;
  const int bn = (blockIdx.x % tiles_n) * BN;
  const int tid  = threadIdx.x;
  const int wave = tid >> 6;
  const int lane = tid & 63;
  const int wm   = (wave & 1) * 64;
  const int wn   = (wave >> 1) * 64;
  const int lrow = lane & 15;
  const int quad = lane >> 4;

  // XOR-swizzled staging: per 64-lane round covering 8 rows x 8 chunks of 16B,
  // lane L -> row (L>>3), LDS physical chunk (L&7), which holds GLOBAL chunk
  // (L&7) ^ (L>>3).  Row stride 128B => read-side bank group = chunk^(row&7),
  // 8 groups x 2 lanes = conflict-free (m136: 2-way is free).
  const int sr     = lane >> 3;              // 0..7
  const int schunk = (lane & 7) ^ sr;        // global 8-col chunk this lane loads
  const int scol   = schunk * 8;             // within [0,64), one 64-col group

  f32x4 acc[4][4];
  #pragma unroll
  for (int i = 0; i < 4; i++)
    #pragma unroll
    for (int j = 0; j < 4; j++) acc[i][j] = (f32x4){0.f, 0.f, 0.f, 0.f};

  for (int k0 = 0; k0 < K; k0 += BK) {
    const long aoff = (long)(k0 >> 6) * a_grp + scol;   // remap (identity when a_grp=64)
    __syncthreads();  // prior compute done before LDS overwrite
    #pragma unroll
    for (int r = 0; r < 4; r++) {
      const int row = wave * 32 + r * 8 + sr;
      gload_lds16(A  + (long)(bm + row) * a_stride + aoff, As + (wave * 32 + r * 8) * BK);
      gload_lds16(BT + (long)(bn + row) * K + k0 + scol,  Bs + (wave * 32 + r * 8) * BK);
    }
    __syncthreads();  // drains vmcnt before ds_read

    #pragma unroll
    for (int kh = 0; kh < 2; kh++) {
      const int xs = lrow & 7;
      short8 a[4], b[4];
      #pragma unroll
      for (int mi = 0; mi < 4; mi++)
        a[mi] = *reinterpret_cast<const short8*>(
            &As[(wm + mi * 16 + lrow) * BK + (((kh * 4 + quad) ^ xs) * 8)]);
      #pragma unroll
      for (int ni = 0; ni < 4; ni++)
        b[ni] = *reinterpret_cast<const short8*>(
            &Bs[(wn + ni * 16 + lrow) * BK + (((kh * 4 + quad) ^ xs) * 8)]);
      #pragma unroll
      for (int mi = 0; mi < 4; mi++)
        #pragma unroll
        for (int ni = 0; ni < 4; ni++)
          acc[mi][ni] = __builtin_amdgcn_mfma_f32_16x16x32_bf16(a[mi], b[ni], acc[mi][ni], 0, 0, 0);
    }
  }

  // epilogue: C/D layout col = lane&15, row = (lane>>4)*4 + r
  #pragma unroll
  for (int ni = 0; ni < 4; ni++) {
    const int col = bn + wn + ni * 16 + lrow;
    const float bv = bias[col];
    #pragma unroll
    for (int mi = 0; mi < 4; mi++) {
      #pragma unroll
      for (int r = 0; r < 4; r++) {
        const int row = bm + wm + mi * 16 + (lane >> 4) * 4 + r;
        const float val = acc[mi][ni][r] + bv;
        if (OUT_F32)
          ((float*)Cv)[(long)row * N + col] = val;
        else
          ((u16*)Cv)[(long)row * N + col] = f2bf(val);
      }
    }
  }
}

// ---------------------------------------------------------------------------
// Per-token attention across the 16 heads. One wave per token.
// qkv row layout: head h -> q at h*192, k at h*192+64, v at h*192+128.
// scores(16x16) via 2 MFMAs straight from global, softmax via intra-quad
// shuffles, PV via VALU with P staged in LDS.  Output written IN PLACE into
// the q-slots (q fully consumed into registers before the write; v disjoint).
// ---------------------------------------------------------------------------
__global__ __launch_bounds__(256) void attn_local(u16* __restrict__ qkv) {
  __shared__ float p_s[4][16][16];
  const int tid  = threadIdx.x;
  const int wave = tid >> 6;
  const int lane = tid & 63;
  const int t    = blockIdx.x * 4 + wave;
  u16* row = qkv + (long)t * THREE_D;
  const int lrow = lane & 15;
  const int quad = lane >> 4;
  const int kq   = quad * 8;

  // A-frag: q[m=lrow][d], B-frag: k[n=lrow][d]  (d = quad*8+j, two 32-chunks)
  short8 a0 = *reinterpret_cast<const short8*>(row + lrow * 192 + kq);
  short8 a1 = *reinterpret_cast<const short8*>(row + lrow * 192 + 32 + kq);
  short8 b0 = *reinterpret_cast<const short8*>(row + lrow * 192 + 64 + kq);
  short8 b1 = *reinterpret_cast<const short8*>(row + lrow * 192 + 96 + kq);
  f32x4 s = {0.f, 0.f, 0.f, 0.f};
  s = __builtin_amdgcn_mfma_f32_16x16x32_bf16(a0, b0, s, 0, 0, 0);
  s = __builtin_amdgcn_mfma_f32_16x16x32_bf16(a1, b1, s, 0, 0, 0);

  const float scale = 0.125f;  // 1/sqrt(64)
  float p[4];
  #pragma unroll
  for (int r = 0; r < 4; r++) {
    // score row i = quad*4+r lives in the 16 lanes of this quad (col = lane&15)
    float x = s[r] * scale;
    float m = x;
    #pragma unroll
    for (int mask = 1; mask < 16; mask <<= 1) m = fmaxf(m, __shfl_xor(m, mask));
    float e = __expf(x - m);
    float l = e;
    #pragma unroll
    for (int mask = 1; mask < 16; mask <<= 1) l += __shfl_xor(l, mask);
    p[r] = e / l;
  }
  #pragma unroll
  for (int r = 0; r < 4; r++) p_s[wave][quad * 4 + r][lrow] = p[r];
  __syncthreads();  // all 4 waves participate (grid is exact)

  // O[i][d=lane] = sum_j P[i][j] * v[j][d]
  float o[16];
  #pragma unroll
  for (int i = 0; i < 16; i++) o[i] = 0.f;
  #pragma unroll
  for (int j = 0; j < 16; j++) {
    float vj = bf2f(row[j * 192 + 128 + lane]);
    #pragma unroll
    for (int i = 0; i < 16; i++) o[i] += p_s[wave][i][j] * vj;
  }
  // in-place write into q-slots: head i, dim lane
  #pragma unroll
  for (int i = 0; i < 16; i++)
    row[i * 192 + lane] = f2bf(o[i]);
}

// ---------------------------------------------------------------------------
extern "C" void kernel_launch(void* const* d_in, const int* in_sizes, int n_in,
                              void* d_out, int out_size, void* d_ws, size_t ws_size,
                              hipStream_t stream) {
  const float* x     = (const float*)d_in[0];  // (T, 1024) f32
  const float* W_qkv = (const float*)d_in[1];  // (1024, 3072) f32
  const float* b_qkv = (const float*)d_in[2];  // (3072) f32
  const float* W_out = (const float*)d_in[3];  // (1024, 1024) f32
  const float* b_out = (const float*)d_in[4];  // (1024) f32
  float* out = (float*)d_out;                  // (T, 1024) f32

  // workspace carve-up: 264 MiB total
  char* ws = (char*)d_ws;
  u16* qkv   = (u16*)ws;  ws += (size_t)TOKENS * THREE_D * 2;   // 192 MiB
  u16* x_bf  = (u16*)ws;  ws += (size_t)TOKENS * DMODEL * 2;    //  64 MiB
  u16* wqkvT = (u16*)ws;  ws += (size_t)THREE_D * DMODEL * 2;   //   6 MiB
  u16* woutT = (u16*)ws;                                        //   2 MiB

  dim3 tb(256);
  convert_f32_bf16<<<dim3((TOKENS * DMODEL) / 1024), tb, 0, stream>>>(
      x, x_bf, (long)TOKENS * DMODEL);
  transpose_convert<<<dim3(THREE_D / 32, DMODEL / 32), tb, 0, stream>>>(W_qkv, wqkvT, DMODEL, THREE_D);
  transpose_convert<<<dim3(DMODEL / 32, DMODEL / 32), tb, 0, stream>>>(W_out, woutT, DMODEL, DMODEL);
  // GEMM1: qkv = x @ W_qkv + b_qkv   (bf16 out, identity A-map)
  gemm_bt_bias<false><<<dim3((TOKENS / BM) * (THREE_D / BN)), tb, 0, stream>>>(
      x_bf, wqkvT, b_qkv, qkv, TOKENS, THREE_D, DMODEL, (long)DMODEL, 64);
  // attention (in place: output -> q-slots of qkv)
  attn_local<<<dim3(TOKENS / 4), tb, 0, stream>>>(qkv);
  // GEMM2: out = vals @ W_out + b_out  (f32 out; A = q-slots: stride 3072, group 192)
  gemm_bt_bias<true><<<dim3((TOKENS / BM) * (DMODEL / BN)), tb, 0, stream>>>(
      qkv, woutT, b_out, out, TOKENS, DMODEL, DMODEL, (long)THREE_D, 192);
}